// Round 5
// baseline (3848.750 us; speedup 1.0000x reference)
//
#include <hip/hip_runtime.h>
#include <math.h>

#define T_TASKS 64
#define NS 75
#define NW 5
#define NTOT 375
#define NQ 150
#define DIM 4096
#define QP_ITERS 15
#define SIGMA 0.1f
#define CREG 0.1f

// workspace layout (float offsets), within the proven 10.1 MB footprint.
// OFF_W region holds gram triangle partials (8*64*2850 fl) before the QP
// solve, then vbuf (1,310,720 fl) after it.
#define OFF_K   0u
#define OFF_W   369664u
#define OFF_Z   2417664u
#define TRI_SZ  2850   // 75*76/2 lower-triangle floats per (chunk, task)

// ------------------------------------------- gram partials, 8 chunks of 512 d.
// 512 blocks (2/CU). Double-buffered LDS, loads issued one sub-chunk ahead.
// Lower triangle only (K symmetric), plain stores, no atomics.
__global__ __launch_bounds__(256) void gram8(const float* __restrict__ support,
                                             float* __restrict__ Kp) {
    int p = blockIdx.x, b = blockIdx.y;
    __shared__ __align__(16) float Ss[2][80][68];
    int tid = threadIdx.x;
    int tx = tid & 15, ty = tid >> 4;
    float acc[5][5];
#pragma unroll
    for (int u = 0; u < 5; u++)
#pragma unroll
        for (int v = 0; v < 5; v++) acc[u][v] = 0.f;
    const float* sb = support + (size_t)b * NS * DIM + p * 512;

    float4 pf[5];
#define G8_ISSUE(c)                                                        \
    {                                                                      \
        _Pragma("unroll")                                                  \
        for (int j = 0; j < 5; j++) {                                      \
            int idx = tid + 256 * j;                                       \
            int r = idx >> 4, q = idx & 15;                                \
            pf[j] = (r < 75) ? *(const float4*)&sb[(size_t)r * DIM + (c) * 64 + q * 4] \
                             : make_float4(0.f, 0.f, 0.f, 0.f);            \
        }                                                                  \
    }
#define G8_COMMIT(c)                                                       \
    {                                                                      \
        _Pragma("unroll")                                                  \
        for (int j = 0; j < 5; j++) {                                      \
            int idx = tid + 256 * j;                                       \
            int r = idx >> 4, q = idx & 15;                                \
            *(float4*)&Ss[(c) & 1][r][q * 4] = pf[j];                      \
        }                                                                  \
    }
    G8_ISSUE(0);
    G8_COMMIT(0);
    for (int c = 0; c < 8; c++) {
        if (c < 7) G8_ISSUE(c + 1);
        __syncthreads();
        for (int d4 = 0; d4 < 16; d4++) {
            float4 av[5], bv[5];
#pragma unroll
            for (int u = 0; u < 5; u++) av[u] = *(const float4*)&Ss[c & 1][ty * 5 + u][d4 * 4];
#pragma unroll
            for (int v = 0; v < 5; v++) bv[v] = *(const float4*)&Ss[c & 1][tx * 5 + v][d4 * 4];
#pragma unroll
            for (int u = 0; u < 5; u++)
#pragma unroll
                for (int v = 0; v < 5; v++)
                    acc[u][v] += av[u].x * bv[v].x + av[u].y * bv[v].y +
                                 av[u].z * bv[v].z + av[u].w * bv[v].w;
        }
        if (c < 7) G8_COMMIT(c + 1);
    }
    float* Ko = Kp + (size_t)(p * 64 + b) * TRI_SZ;
#pragma unroll
    for (int u = 0; u < 5; u++) {
        int row = ty * 5 + u;
#pragma unroll
        for (int v = 0; v < 5; v++) {
            int col = tx * 5 + v;
            if (row < 75 && col < 75 && row >= col)
                Ko[row * (row + 1) / 2 + col] = acc[u][v];
        }
    }
}

// reduce 8 triangle partials into padded symmetric Kg (pad diag = 1)
__global__ void gram_reduce(const float* __restrict__ Kp, float* __restrict__ Kg) {
    int idx = blockIdx.x * 256 + threadIdx.x;
    if (idx >= T_TASKS * 5776) return;
    int b = idx / 5776, rc = idx % 5776;
    int row = rc / 76, col = rc % 76;
    float val;
    if (row < 75 && col < 75) {
        int i = row > col ? row : col, j = row > col ? col : row;
        int t = i * (i + 1) / 2 + j;
        val = 0.f;
#pragma unroll
        for (int p = 0; p < 8; p++)
            val += Kp[(size_t)(p * 64 + b) * TRI_SZ + t];
    } else {
        val = (row == col) ? 1.f : 0.f;
    }
    Kg[idx] = val;
}

// --------------- WAVE-AUTONOMOUS Gauss-Jordan inverse of one 80x80 matrix.
// One 64-lane wave owns the whole matrix: lane (rb=l>>3, cb=l&7) holds the
// 10x10 sub-grid (rb+8i, cb+8j) in VGPRs (static indexing only: unrolled
// if(rb+8i==k) guards). Row/col-k broadcast goes through wave-PRIVATE LDS
// buffers; same-wave DS ordering (lgkmcnt) replaces __syncthreads -> the
// 75-step pivot chain has ZERO barriers. Column-pre-fix rank-1 update
// (verified algebra from the round-2 kernel). Pivots k<75; pads identity.
__device__ __forceinline__ void gj_wave(float (&M)[10][10],
                                        float (*rbuf)[80], float (*cbuf)[80],
                                        int rb, int cb) {
    for (int k = 0; k < 75; k++) {
        int buf = k & 1;
        int k8 = k & 7;
        if (rb == k8) {
#pragma unroll
            for (int i = 0; i < 10; i++)
                if (rb + 8 * i == k) {
#pragma unroll
                    for (int j = 0; j < 10; j++) rbuf[buf][cb + 8 * j] = M[i][j];
                }
        }
        if (cb == k8) {
#pragma unroll
            for (int j = 0; j < 10; j++)
                if (cb + 8 * j == k) {
#pragma unroll
                    for (int i = 0; i < 10; i++) cbuf[buf][rb + 8 * i] = M[i][j];
                }
        }
        // same-wave LDS write->read: compiler-inserted lgkmcnt orders this.
        float pinv = 1.f / rbuf[buf][k];
        // column-k pre-fix: M[:,k] := e_k
        if (cb == k8) {
#pragma unroll
            for (int j = 0; j < 10; j++)
                if (cb + 8 * j == k) {
#pragma unroll
                    for (int i = 0; i < 10; i++)
                        M[i][j] = (rb + 8 * i == k) ? 1.f : 0.f;
                }
        }
        float pv[10], fv[10];
#pragma unroll
        for (int j = 0; j < 10; j++) {
            int c = cb + 8 * j;
            float p = rbuf[buf][c];
            pv[j] = (c == k) ? 1.f : p;
        }
#pragma unroll
        for (int i = 0; i < 10; i++) {
            int r = rb + 8 * i;
            float f = cbuf[buf][r] * pinv;
            fv[i] = (r == k) ? (1.f - pinv) : f;
        }
#pragma unroll
        for (int i = 0; i < 10; i++)
#pragma unroll
            for (int j = 0; j < 10; j++) M[i][j] -= fv[i] * pv[j];
    }
}

// ------------------------------------- one block (384 thr = 6 waves) per task.
// Waves 0-4: invert H_w barrier-free (one per wave). Wave 5: invert S.
// State LDS-resident; K staged in LDS once; ~7 block barriers per iteration
// (vs 150 in the previous version). Zero global traffic in the loop.
__global__ __launch_bounds__(384, 1) void qp_solve(
        const float* __restrict__ Kg, const int* __restrict__ labels,
        float* __restrict__ zout) {
    int b = blockIdx.x;
    int tid = threadIdx.x;
    int wid = tid >> 6, lane = tid & 63;
    int rb = lane >> 3, cb = lane & 7;

    __shared__ float Klds[76 * 77];           // padded stride 77
    __shared__ float Sbuf[80 * 81];           // padded stride 81
    __shared__ float rowb[6][2][80], colb[6][2][80];
    __shared__ float zs[400], ss[400], ls[400];
    __shared__ float nus[80];
    __shared__ float r1w[5][80], Dbuf[5][80], tvs[5][80], dzs[5][80];
    __shared__ float rhs[80], dnu[80];
    __shared__ float mred[6], ared[6];
    __shared__ int labv[80];

    // stage K into LDS (row-major, stride 77)
    for (int idx = tid; idx < 76 * 76; idx += 384) {
        int r = idx / 76, c = idx - r * 76;
        Klds[r * 77 + c] = Kg[(size_t)b * 5776 + idx];
    }
    for (int idx = tid; idx < 400; idx += 384) {
        zs[idx] = 0.f;
        ss[idx] = (idx < NTOT) ? 1.f : 0.f;
        ls[idx] = (idx < NTOT) ? 1.f : 0.f;
    }
    if (tid < 80) {
        nus[tid] = 0.f;
        labv[tid] = (tid < 75) ? labels[b * NS + tid] : -1;
    }
    __syncthreads();

    float M[10][10];     // 100 VGPRs: K -> H_w -> W_w   (wave 5: S -> S^-1)
    float treg[10];      // t_w = W_w r1_w (lives across S-inv)

    for (int it = 0; it < QP_ITERS; it++) {
        // ---- mu = mean(lam*s)
        {
            float part = (tid < NTOT) ? ls[tid] * ss[tid] : 0.f;
#pragma unroll
            for (int off = 32; off > 0; off >>= 1) part += __shfl_xor(part, off, 64);
            if (lane == 0) mred[wid] = part;
        }
        __syncthreads();                                             // B1
        float mu = (mred[0] + mred[1] + mred[2] + mred[3] + mred[4] + mred[5])
                   * (1.f / (float)NTOT);

        if (wid < 5) {
            int w = wid;
            // K -> regs (pads >=76 identity; Kg pads row/col 75 already)
#pragma unroll
            for (int i = 0; i < 10; i++) {
                int r = rb + 8 * i;
#pragma unroll
                for (int j = 0; j < 10; j++) {
                    int c = cb + 8 * j;
                    M[i][j] = (r < 76 && c < 76) ? Klds[r * 77 + c]
                                                 : ((r == c) ? 1.f : 0.f);
                }
            }
            // gz = K z_w
            float zv[10], gz[10];
#pragma unroll
            for (int j = 0; j < 10; j++) zv[j] = zs[(cb + 8 * j) * 5 + w];
#pragma unroll
            for (int i = 0; i < 10; i++) {
                float a = 0.f;
#pragma unroll
                for (int j = 0; j < 10; j++) a += M[i][j] * zv[j];
                gz[i] = a;
            }
#pragma unroll
            for (int off = 1; off < 8; off <<= 1)
#pragma unroll
                for (int i = 0; i < 10; i++) gz[i] += __shfl_xor(gz[i], off, 64);
            if (cb == 0) {
#pragma unroll
                for (int i = 0; i < 10; i++) {
                    int r = rb + 8 * i;
                    float val = 0.f, dv = 0.f;
                    if (r < 75) {
                        float sv = ss[r * 5 + w], lv = ls[r * 5 + w], zl = zs[r * 5 + w];
                        float e = (labv[r] == w) ? -1.f : 0.f;
                        float h = (labv[r] == w) ? CREG : 0.f;
                        float rz = gz[i] + zl + e + lv + nus[r];
                        float rsv = zl + sv - h;
                        val = -rz - (lv * rsv - lv * sv + SIGMA * mu) / sv;
                        dv = lv / sv;
                    }
                    r1w[w][r] = val;
                    Dbuf[w][r] = dv;
                }
            }
            // H_w = K + I + diag(D_w)  (same-wave LDS, lgkm-ordered)
            if (rb == cb) {
#pragma unroll
                for (int i = 0; i < 10; i++) {
                    int r = rb + 8 * i;
                    if (r < 75) M[i][i] += 1.f + Dbuf[w][r];
                }
            }
            // barrier-free inversion
            gj_wave(M, rowb[w], colb[w], rb, cb);
            // t_w = W_w r1_w
            float rv[10];
#pragma unroll
            for (int j = 0; j < 10; j++) rv[j] = r1w[w][cb + 8 * j];
#pragma unroll
            for (int i = 0; i < 10; i++) {
                float a = 0.f;
#pragma unroll
                for (int j = 0; j < 10; j++) a += M[i][j] * rv[j];
                treg[i] = a;
            }
#pragma unroll
            for (int off = 1; off < 8; off <<= 1)
#pragma unroll
                for (int i = 0; i < 10; i++) treg[i] += __shfl_xor(treg[i], off, 64);
            if (cb == 0) {
#pragma unroll
                for (int i = 0; i < 10; i++) tvs[w][rb + 8 * i] = treg[i];
            }
        } else {
            // wave 5: zero the S accumulator while waves 0-4 invert
            for (int idx = lane; idx < 80 * 81; idx += 64) Sbuf[idx] = 0.f;
        }
        __syncthreads();                                             // B2
        if (wid < 5) {
#pragma unroll
            for (int i = 0; i < 10; i++)
#pragma unroll
                for (int j = 0; j < 10; j++)
                    atomicAdd(&Sbuf[(rb + 8 * i) * 81 + cb + 8 * j], M[i][j]);
        }
        __syncthreads();                                             // B3
        if (wid == 5) {
            for (int r = lane; r < 80; r += 64) {
                float rv2 = 0.f;
                if (r < 75) {
#pragma unroll
                    for (int w = 0; w < 5; w++) rv2 += zs[r * 5 + w] + tvs[w][r];
                }
                rhs[r] = rv2;
            }
#pragma unroll
            for (int i = 0; i < 10; i++)
#pragma unroll
                for (int j = 0; j < 10; j++)
                    M[i][j] = Sbuf[(rb + 8 * i) * 81 + cb + 8 * j];
            gj_wave(M, rowb[5], colb[5], rb, cb);
            // dnu = S^-1 rhs
            float rv[10], ac[10];
#pragma unroll
            for (int j = 0; j < 10; j++) rv[j] = rhs[cb + 8 * j];
#pragma unroll
            for (int i = 0; i < 10; i++) {
                float a = 0.f;
#pragma unroll
                for (int j = 0; j < 10; j++) a += M[i][j] * rv[j];
                ac[i] = a;
            }
#pragma unroll
            for (int off = 1; off < 8; off <<= 1)
#pragma unroll
                for (int i = 0; i < 10; i++) ac[i] += __shfl_xor(ac[i], off, 64);
            if (cb == 0) {
#pragma unroll
                for (int i = 0; i < 10; i++) dnu[rb + 8 * i] = ac[i];
            }
        }
        __syncthreads();                                             // B4
        if (wid < 5) {
            // dz_w = t_w - W_w dnu
            float uv[10], ac[10];
#pragma unroll
            for (int j = 0; j < 10; j++) uv[j] = dnu[cb + 8 * j];
#pragma unroll
            for (int i = 0; i < 10; i++) {
                float a = 0.f;
#pragma unroll
                for (int j = 0; j < 10; j++) a += M[i][j] * uv[j];
                ac[i] = a;
            }
#pragma unroll
            for (int off = 1; off < 8; off <<= 1)
#pragma unroll
                for (int i = 0; i < 10; i++) ac[i] += __shfl_xor(ac[i], off, 64);
            if (cb == 0) {
#pragma unroll
                for (int i = 0; i < 10; i++) dzs[wid][rb + 8 * i] = treg[i] - ac[i];
            }
        }
        __syncthreads();                                             // B5
        // ---- elementwise ds/dlam + step length
        float rat = INFINITY;
        float dzv = 0.f, dsv = 0.f, dlv = 0.f, zl = 0.f, sl = 1.f, ll = 0.f;
        int c = tid;
        if (c < NTOT) {
            int i = c / 5, w = c - i * 5;
            dzv = dzs[w][i];
            zl = zs[c]; sl = ss[c]; ll = ls[c];
            float h = (labv[i] == w) ? CREG : 0.f;
            float rsv = zl + sl - h;
            dsv = -rsv - dzv;
            dlv = (ll * dzv + ll * rsv - ll * sl + SIGMA * mu) / sl;
            float rr1 = (dsv < 0.f) ? (-sl / dsv) : INFINITY;
            float rr2 = (dlv < 0.f) ? (-ll / dlv) : INFINITY;
            rat = fminf(rr1, rr2);
        }
#pragma unroll
        for (int off = 32; off > 0; off >>= 1) rat = fminf(rat, __shfl_xor(rat, off, 64));
        if (lane == 0) ared[wid] = rat;
        __syncthreads();                                             // B6
        float alpha = fminf(1.f, 0.99f * fminf(fminf(fminf(ared[0], ared[1]),
                                                     fminf(ared[2], ared[3])),
                                               fminf(ared[4], ared[5])));
        if (c < NTOT) {
            zs[c] = zl + alpha * dzv;
            ss[c] = sl + alpha * dsv;
            ls[c] = ll + alpha * dlv;
        }
        if (tid < 75) nus[tid] += alpha * dnu[tid];
        __syncthreads();                                             // B7
    }

    for (int idx = tid; idx < NTOT; idx += 384) zout[b * NTOT + idx] = zs[idx];
}

// ------------------------------ v[b,w,:] = sum_s z[b,s,w] * support[b,s,:]
__global__ __launch_bounds__(256) void v_kernel(const float* __restrict__ support,
                                                const float* __restrict__ z,
                                                float* __restrict__ vbuf) {
    int dc = blockIdx.x, b = blockIdx.y;
    __shared__ float zsm[NTOT];
    int tid = threadIdx.x;
    for (int idx = tid; idx < NTOT; idx += 256) zsm[idx] = z[b * NTOT + idx];
    __syncthreads();
    int d = dc * 256 + tid;
    float acc[5] = {0.f, 0.f, 0.f, 0.f, 0.f};
    const float* sb = support + (size_t)b * NS * DIM + d;
    for (int ssi = 0; ssi < NS; ssi++) {
        float svv = sb[(size_t)ssi * DIM];
#pragma unroll
        for (int w = 0; w < 5; w++) acc[w] += svv * zsm[ssi * 5 + w];
    }
#pragma unroll
    for (int w = 0; w < 5; w++) vbuf[(size_t)(b * NW + w) * DIM + d] = acc[w];
}

// -------------------- logits[b,q,w] = sum_d query[b,q,d] * v[b,w,d]
__global__ __launch_bounds__(256) void logits_kernel(const float* __restrict__ query,
                                                     const float* __restrict__ vbuf,
                                                     float* __restrict__ out) {
    int qt = blockIdx.x, b = blockIdx.y;
    __shared__ __align__(16) float vs[5 * 1028];
    int tid = threadIdx.x;
    int lane = tid & 63, wid = tid >> 6;
    float acc[8][5];
#pragma unroll
    for (int r = 0; r < 8; r++)
#pragma unroll
        for (int w = 0; w < 5; w++) acc[r][w] = 0.f;

    for (int c = 0; c < 4; c++) {
        __syncthreads();
        for (int idx = tid; idx < 5120; idx += 256) {
            int w = idx >> 10, dd = idx & 1023;
            vs[w * 1028 + dd] = vbuf[(size_t)(b * NW + w) * DIM + c * 1024 + dd];
        }
        __syncthreads();
#pragma unroll
        for (int ri = 0; ri < 8; ri++) {
            int r = wid + ri * 4;
            if (r < 30) {
                int q = qt * 30 + r;
                const float* qp = query + (size_t)(b * NQ + q) * DIM + c * 1024;
#pragma unroll
                for (int j = 0; j < 4; j++) {
                    int d = lane * 4 + j * 256;
                    float4 qv = *(const float4*)(qp + d);
#pragma unroll
                    for (int w = 0; w < 5; w++) {
                        float4 vv = *(const float4*)(&vs[w * 1028 + d]);
                        acc[ri][w] += qv.x * vv.x + qv.y * vv.y + qv.z * vv.z + qv.w * vv.w;
                    }
                }
            }
        }
    }
#pragma unroll
    for (int ri = 0; ri < 8; ri++) {
        int r = wid + ri * 4;
#pragma unroll
        for (int w = 0; w < 5; w++) {
            float v = acc[ri][w];
            for (int off = 32; off > 0; off >>= 1) v += __shfl_xor(v, off, 64);
            if (r < 30 && lane == 0)
                out[(size_t)(b * NQ + qt * 30 + r) * NW + w] = v;
        }
    }
}

// ---------------------------------------------------------------------------
extern "C" void kernel_launch(void* const* d_in, const int* in_sizes, int n_in,
                              void* d_out, int out_size, void* d_ws, size_t ws_size,
                              hipStream_t stream) {
    const float* query   = (const float*)d_in[0];
    const float* support = (const float*)d_in[1];
    const int*   labels  = (const int*)d_in[2];
    float* out = (float*)d_out;
    float* ws  = (float*)d_ws;

    float* Kg   = ws + OFF_K;
    float* Kp   = ws + OFF_W;   // gram triangle partials (dead after reduce)
    float* vbuf = ws + OFF_W;   // alias (live after QP)
    float* z    = ws + OFF_Z;

    gram8<<<dim3(8, T_TASKS), 256, 0, stream>>>(support, Kp);
    gram_reduce<<<(T_TASKS * 5776 + 255) / 256, 256, 0, stream>>>(Kp, Kg);
    qp_solve<<<T_TASKS, 384, 0, stream>>>(Kg, labels, z);
    v_kernel<<<dim3(16, T_TASKS), 256, 0, stream>>>(support, z, vbuf);
    logits_kernel<<<dim3(5, T_TASKS), 256, 0, stream>>>(query, vbuf, out);
}